// Round 7
// baseline (45.649 us; speedup 1.0000x reference)
//
#include <hip/hip_runtime.h>

// out = w*cumprod(cos(x+pe), axis=-1) + (1-w)*(x+pe)
// x[B=16,S=4096,D=512] f32, qw scalar. pe computed on the fly:
//   pe[s,2k]=sin(s*div_k), pe[s,2k+1]=cos(s*div_k), div_k=10000^(-k/256),
//   k = lane*4+j (each lane owns 4 sin/cos pairs of its 8 elements).
//
// Trajectory: R6 (plain stores, 4 rows/wave = 8 loads in flight) hit 44.8us,
// 4.4 TB/s HBM. The R5->R6 gain came purely from per-wave MLP, so R7 doubles
// it again: 8 rows/wave, 16 independent dwordx4 loads issued up front,
// per-row store-as-ready. 2048 blocks = exactly 8 blocks/CU.
constexpr int D = 512;
constexpr int S = 4096;
constexpr int B = 16;
constexpr int ROWS = B * S;            // 65536
constexpr int WAVES_PER_BLOCK = 4;     // 256-thread blocks
constexpr int ROWS_PER_WAVE  = 8;      // 16 loads in flight, 8 scan chains

typedef float fx4 __attribute__((ext_vector_type(4)));

// --- DPP multiply-scan (gfx9: row_shr / row_bcast / wave_shr), pure VALU ---
template<int CTRL, int ROW_MASK>
__device__ __forceinline__ float dpp_mul(float x) {
    int t = __builtin_amdgcn_update_dpp(0x3f800000, __float_as_int(x),
                                        CTRL, ROW_MASK, 0xF, false);
    return x * __int_as_float(t);
}
__device__ __forceinline__ float wave_incl_mul_scan(float p) {
    p = dpp_mul<0x111, 0xF>(p);   // row_shr:1
    p = dpp_mul<0x112, 0xF>(p);   // row_shr:2
    p = dpp_mul<0x114, 0xF>(p);   // row_shr:4
    p = dpp_mul<0x118, 0xF>(p);   // row_shr:8
    p = dpp_mul<0x142, 0xA>(p);   // row_bcast:15 -> rows 1,3
    p = dpp_mul<0x143, 0xC>(p);   // row_bcast:31 -> rows 2,3
    return p;
}
__device__ __forceinline__ float wave_shr1_id(float p) {
    int t = __builtin_amdgcn_update_dpp(0x3f800000, __float_as_int(p),
                                        0x138 /*wave_shr:1*/, 0xF, 0xF, false);
    return __int_as_float(t);
}

__global__ __launch_bounds__(256) void qpe_kernel(
    const fx4* __restrict__ x4, const float* __restrict__ qw,
    fx4* __restrict__ out4)
{
    const int lane = threadIdx.x & 63;
    const int wid  = threadIdx.x >> 6;
    const int wave = blockIdx.x * WAVES_PER_BLOCK + wid;
    const int row0 = wave * ROWS_PER_WAVE;

    const float w   = 1.0f / (1.0f + __expf(-qw[0]));
    const float omw = 1.0f - w;

    // Per-lane frequencies: div_j = 10000^(-(lane*4+j)/256) = exp2(k * c).
    const float NEG_LOG2_10K_OVER_256 = -0.05190512648261503f; // -log2(1e4)/256
    float div[4];
    #pragma unroll
    for (int j = 0; j < 4; ++j)
        div[j] = exp2f((float)(lane * 4 + j) * NEG_LOG2_10K_OVER_256);

    // Issue ALL x loads up front (8 rows x 2 fx4 = 16 independent 16B loads).
    size_t xb[ROWS_PER_WAVE];
    fx4 xv[ROWS_PER_WAVE][2];
    #pragma unroll
    for (int r = 0; r < ROWS_PER_WAVE; ++r) {
        xb[r] = (size_t)(row0 + r) * (D / 4) + (size_t)lane * 2;
        xv[r][0] = x4[xb[r]];
        xv[r][1] = x4[xb[r] + 1];
    }

    // Per row: pe-trig + add + cos + local product + DPP scan + blend + store.
    // Rows independent; storing each as soon as it's done overlaps the write
    // stream with the remaining rows' ALU work (and frees its registers).
    #pragma unroll
    for (int r = 0; r < ROWS_PER_WAVE; ++r) {
        const float sf = (float)((row0 + r) & (S - 1));   // position s
        float o[8], c[8];
        {
            float xr[8] = { xv[r][0][0], xv[r][0][1], xv[r][0][2], xv[r][0][3],
                            xv[r][1][0], xv[r][1][1], xv[r][1][2], xv[r][1][3] };
            #pragma unroll
            for (int j = 0; j < 4; ++j) {
                const float a = sf * div[j];
                o[2 * j]     = xr[2 * j]     + __sinf(a);
                o[2 * j + 1] = xr[2 * j + 1] + __cosf(a);
            }
        }
        #pragma unroll
        for (int j = 0; j < 8; ++j) c[j] = __cosf(o[j]);

        float p = c[0];
        #pragma unroll
        for (int j = 1; j < 8; ++j) p *= c[j];

        p = wave_incl_mul_scan(p);
        p = wave_shr1_id(p);                       // exclusive prefix, lane0=1

        float run = p, res[8];
        #pragma unroll
        for (int j = 0; j < 8; ++j) {
            run *= c[j];
            res[j] = w * run + omw * o[j];
        }
        out4[xb[r]]     = (fx4){ res[0], res[1], res[2], res[3] };
        out4[xb[r] + 1] = (fx4){ res[4], res[5], res[6], res[7] };
    }
}

extern "C" void kernel_launch(void* const* d_in, const int* in_sizes, int n_in,
                              void* d_out, int out_size, void* d_ws, size_t ws_size,
                              hipStream_t stream) {
    const fx4* x  = (const fx4*)d_in[0];
    // d_in[1] = pe (recomputed on device), d_in[2] = param (unused)
    const float* qw  = (const float*)d_in[3];
    fx4* out = (fx4*)d_out;

    const int blocks = ROWS / (WAVES_PER_BLOCK * ROWS_PER_WAVE); // 2048
    qpe_kernel<<<blocks, WAVES_PER_BLOCK * 64, 0, stream>>>(x, qw, out);
}

// Round 8
// 45.091 us; speedup vs baseline: 1.0124x; 1.0124x over previous
//
#include <hip/hip_runtime.h>

// out = w*cumprod(cos(x+pe), axis=-1) + (1-w)*(x+pe)
// x[B=16,S=4096,D=512] f32, qw scalar. pe computed on the fly:
//   pe[s,2k]=sin(s*div_k), pe[s,2k+1]=cos(s*div_k), div_k=10000^(-k/256),
//   k = lane*4+j (each lane owns 4 sin/cos pairs of its 8 elements).
//
// R7 lesson: VGPR_Count=32 proved the compiler SANK the "issued up front"
// loads into the per-row loop (holding 4-8 rows needs 32-64 data VGPRs) —
// the MLP increase never reached hardware; R6==R7. R8 pins program order
// with sched_barrier(0) after the load loop so all 8 dwordx4 stay in
// flight, at the cost of VGPR ~64-80 (still 6+ waves/SIMD).
constexpr int D = 512;
constexpr int S = 4096;
constexpr int B = 16;
constexpr int ROWS = B * S;            // 65536
constexpr int WAVES_PER_BLOCK = 4;     // 256-thread blocks
constexpr int ROWS_PER_WAVE  = 4;      // R6 config (best so far)

typedef float fx4 __attribute__((ext_vector_type(4)));

// --- DPP multiply-scan (gfx9: row_shr / row_bcast / wave_shr), pure VALU ---
template<int CTRL, int ROW_MASK>
__device__ __forceinline__ float dpp_mul(float x) {
    int t = __builtin_amdgcn_update_dpp(0x3f800000, __float_as_int(x),
                                        CTRL, ROW_MASK, 0xF, false);
    return x * __int_as_float(t);
}
__device__ __forceinline__ float wave_incl_mul_scan(float p) {
    p = dpp_mul<0x111, 0xF>(p);   // row_shr:1
    p = dpp_mul<0x112, 0xF>(p);   // row_shr:2
    p = dpp_mul<0x114, 0xF>(p);   // row_shr:4
    p = dpp_mul<0x118, 0xF>(p);   // row_shr:8
    p = dpp_mul<0x142, 0xA>(p);   // row_bcast:15 -> rows 1,3
    p = dpp_mul<0x143, 0xC>(p);   // row_bcast:31 -> rows 2,3
    return p;
}
__device__ __forceinline__ float wave_shr1_id(float p) {
    int t = __builtin_amdgcn_update_dpp(0x3f800000, __float_as_int(p),
                                        0x138 /*wave_shr:1*/, 0xF, 0xF, false);
    return __int_as_float(t);
}

__global__ __launch_bounds__(256) void qpe_kernel(
    const fx4* __restrict__ x4, const float* __restrict__ qw,
    fx4* __restrict__ out4)
{
    const int lane = threadIdx.x & 63;
    const int wid  = threadIdx.x >> 6;
    const int wave = blockIdx.x * WAVES_PER_BLOCK + wid;
    const int row0 = wave * ROWS_PER_WAVE;

    // Issue ALL x loads first (4 rows x 2 fx4 = 8 independent 16B loads)...
    size_t xb[ROWS_PER_WAVE];
    fx4 xv[ROWS_PER_WAVE][2];
    #pragma unroll
    for (int r = 0; r < ROWS_PER_WAVE; ++r) {
        xb[r] = (size_t)(row0 + r) * (D / 4) + (size_t)lane * 2;
        xv[r][0] = x4[xb[r]];
        xv[r][1] = x4[xb[r] + 1];
    }
    // ...and PIN them above all compute: without this the scheduler sinks
    // the loads into the row loop to cap VGPR at 32 (proved by R6/R7
    // VGPR_Count) and only ~2 loads stay in flight.
    __builtin_amdgcn_sched_barrier(0);

    const float w   = 1.0f / (1.0f + __expf(-qw[0]));
    const float omw = 1.0f - w;

    // Per-lane frequencies: div_j = 10000^(-(lane*4+j)/256) = exp2(k * c).
    const float NEG_LOG2_10K_OVER_256 = -0.05190512648261503f; // -log2(1e4)/256
    float div[4];
    #pragma unroll
    for (int j = 0; j < 4; ++j)
        div[j] = exp2f((float)(lane * 4 + j) * NEG_LOG2_10K_OVER_256);

    // Per row: pe-trig + add + cos + local product + DPP scan + blend + store.
    #pragma unroll
    for (int r = 0; r < ROWS_PER_WAVE; ++r) {
        const float sf = (float)((row0 + r) & (S - 1));   // position s
        float o[8], c[8];
        {
            float xr[8] = { xv[r][0][0], xv[r][0][1], xv[r][0][2], xv[r][0][3],
                            xv[r][1][0], xv[r][1][1], xv[r][1][2], xv[r][1][3] };
            #pragma unroll
            for (int j = 0; j < 4; ++j) {
                const float a = sf * div[j];
                o[2 * j]     = xr[2 * j]     + __sinf(a);
                o[2 * j + 1] = xr[2 * j + 1] + __cosf(a);
            }
        }
        #pragma unroll
        for (int j = 0; j < 8; ++j) c[j] = __cosf(o[j]);

        float p = c[0];
        #pragma unroll
        for (int j = 1; j < 8; ++j) p *= c[j];

        p = wave_incl_mul_scan(p);
        p = wave_shr1_id(p);                       // exclusive prefix, lane0=1

        float run = p, res[8];
        #pragma unroll
        for (int j = 0; j < 8; ++j) {
            run *= c[j];
            res[j] = w * run + omw * o[j];
        }
        out4[xb[r]]     = (fx4){ res[0], res[1], res[2], res[3] };
        out4[xb[r] + 1] = (fx4){ res[4], res[5], res[6], res[7] };
    }
}

extern "C" void kernel_launch(void* const* d_in, const int* in_sizes, int n_in,
                              void* d_out, int out_size, void* d_ws, size_t ws_size,
                              hipStream_t stream) {
    const fx4* x  = (const fx4*)d_in[0];
    // d_in[1] = pe (recomputed on device), d_in[2] = param (unused)
    const float* qw  = (const float*)d_in[3];
    fx4* out = (fx4*)d_out;

    const int blocks = ROWS / (WAVES_PER_BLOCK * ROWS_PER_WAVE); // 4096
    qpe_kernel<<<blocks, WAVES_PER_BLOCK * 64, 0, stream>>>(x, qw, out);
}